// Round 1
// 232.002 us; speedup vs baseline: 1.0840x; 1.0840x over previous
//
#include <hip/hip_runtime.h>
#include <cstdint>

typedef __bf16 bf16;
typedef __bf16 bf16x8 __attribute__((ext_vector_type(8)));
typedef float f32x4 __attribute__((ext_vector_type(4)));

#define MFMA16(a, b, c) __builtin_amdgcn_mfma_f32_16x16x32_bf16((a), (b), (c), 0, 0, 0)
#define GLDS16(g, l)                                                         \
  __builtin_amdgcn_global_load_lds(                                          \
      (__attribute__((address_space(1))) void*)(g),                          \
      (__attribute__((address_space(3))) void*)(l), 16, 0, 0)

// ---- one prep kernel: 6 weight transposes + x/ctx/img casts (grid z=11) ----
__global__ void prep_all(const float* __restrict__ Wq, const float* __restrict__ Wo,
                         const float* __restrict__ Wk, const float* __restrict__ Wv,
                         const float* __restrict__ Wkip, const float* __restrict__ Wvip,
                         bf16* __restrict__ WqT, bf16* __restrict__ WoT,
                         bf16* __restrict__ WkT, bf16* __restrict__ WvT,
                         bf16* __restrict__ WkipT, bf16* __restrict__ WvipT,
                         const float* __restrict__ x, bf16* __restrict__ xb,
                         const float* __restrict__ ctx, bf16* __restrict__ ctxb,
                         const float* __restrict__ img, bf16* __restrict__ imgb) {
  const int z = blockIdx.z;
  const int tx = threadIdx.x, ty = threadIdx.y;
  if (z < 6) {
    const float* src = (z == 0) ? Wq : (z == 1) ? Wo : (z == 2) ? Wk
                      : (z == 3) ? Wv : (z == 4) ? Wkip : Wvip;
    bf16* dst = (z == 0) ? WqT : (z == 1) ? WoT : (z == 2) ? WkT
               : (z == 3) ? WvT : (z == 4) ? WkipT : WvipT;
    const int K = (z < 2) ? 1280 : 2048;
    const int N = 1280;
    __shared__ float t[32][33];
    const int bx = blockIdx.x * 32, by = blockIdx.y * 32;
    if (by >= K) return;
#pragma unroll
    for (int i = 0; i < 32; i += 8)
      t[ty + i][tx] = src[(long)(by + ty + i) * N + bx + tx];
    __syncthreads();
#pragma unroll
    for (int i = 0; i < 32; i += 8)
      dst[(long)(bx + ty + i) * K + by + tx] = (bf16)t[tx][ty + i];
    return;
  }
  const int tid = ty * 32 + tx;
  const int bid = blockIdx.y * 40 + blockIdx.x;  // 0..2559
  const float* s;
  bf16* d;
  long base;
  if (z < 10) {  // x: 4 slices x 2560 blocks x 2048 elems = 20971520 exact
    base = (((long)(z - 6) * 2560 + bid) * 256 + tid) * 8;
    s = x; d = xb;
  } else if (bid < 308) {  // ctx: 308*2048 = 630784 exact
    base = ((long)bid * 256 + tid) * 8;
    s = ctx; d = ctxb;
  } else if (bid < 372) {  // img: 64*2048 = 131072 exact
    base = ((long)(bid - 308) * 256 + tid) * 8;
    s = img; d = imgb;
  } else {
    return;
  }
  float4 a = *(const float4*)(s + base);
  float4 b = *(const float4*)(s + base + 4);
  bf16x8 o;
  o[0] = (bf16)a.x; o[1] = (bf16)a.y; o[2] = (bf16)a.z; o[3] = (bf16)a.w;
  o[4] = (bf16)b.x; o[5] = (bf16)b.y; o[6] = (bf16)b.z; o[7] = (bf16)b.w;
  *(bf16x8*)(d + base) = o;
}

// ------ tri-buffered pipelined GEMM: C = A[M,K] @ Bt[N,K]^T ------
// 256 thr = 4 waves, tile 128x128, BK=32. Swizzle verified (R4, conflicts=0).
// 3 slots x 16KB (48KB -> 3 WG/CU), depth-2 prefetch, 1 barrier/K-step,
// ds_reads for tile t+1 issued BEFORE tile t's MFMA cluster.
// Iter t (slot slc=t%3): lgkm(0) [READS(t) done] ; stage(t+2 -> (t+2)%3) ;
//   vmcnt(4) [outstanding t+1,t+2=8 -> oldest 4 = t+1 landed] ; barrier ;
//   READS(t+1 from (t+1)%3) ; SB ; 16 MFMA(t).
// WAR stage(t+2)->slot(t-1)%3: tile-(t-1) reads completed at every wave's
// top-of-(t-1) lgkm(0) < barrier(t-1) < any wave's iter-t stage.  NT even.
template <bool OUT_BF16, bool HAS_BIAS>
__device__ __forceinline__ void gemm_bt_core(const bf16* A, const bf16* Bt,
                                             void* Cp, const float* bias,
                                             int K, int N, int tm, int tn) {
  __shared__ bf16 Al[3][128 * 32];
  __shared__ bf16 Bl[3][128 * 32];
  const int tid = threadIdx.x;
  const int wave = tid >> 6, lane = tid & 63;
  const int g = lane >> 4, l16 = lane & 15;

  const int sr = lane >> 2;
  const int sc = ((lane & 3) ^ ((lane >> 3) & 3)) * 8;  // source pre-swizzle
  const bf16* ga0 = A + (long)(tm + wave * 16 + sr) * K + sc;
  const bf16* ga1 = ga0 + (long)64 * K;
  const bf16* gb0 = Bt + (long)(tn + wave * 16 + sr) * K + sc;
  const bf16* gb1 = gb0 + (long)64 * K;

  f32x4 acc[4][4] = {};
  const int wr = (wave >> 1) * 64, wc = (wave & 1) * 64;
  const int rsw = (g ^ ((l16 >> 1) & 3)) * 8;  // read-side swizzle
  const int paOfs = (wr + l16) * 32 + rsw;
  const int pbOfs = (wc + l16) * 32 + rsw;

  const int NT = K >> 5;  // even (40 or 64)

#define STAGE_TILE(t_, b_)                              \
  {                                                     \
    const int kt_ = (t_) << 5;                          \
    GLDS16(ga0 + kt_, &Al[b_][wave * 512]);             \
    GLDS16(ga1 + kt_, &Al[b_][(wave + 4) * 512]);       \
    GLDS16(gb0 + kt_, &Bl[b_][wave * 512]);             \
    GLDS16(gb1 + kt_, &Bl[b_][(wave + 4) * 512]);       \
  }

#define READS(sl_, af_, bf_)                                      \
  {                                                               \
    const bf16* pa_ = &Al[sl_][paOfs];                            \
    const bf16* pb_ = &Bl[sl_][pbOfs];                            \
    _Pragma("unroll") for (int i_ = 0; i_ < 4; i_++)              \
        af_[i_] = *(const bf16x8*)(pa_ + i_ * 16 * 32);           \
    _Pragma("unroll") for (int j_ = 0; j_ < 4; j_++)              \
        bf_[j_] = *(const bf16x8*)(pb_ + j_ * 16 * 32);           \
  }

  // prologue: tiles 0,1 -> slots 0,1; tile0 landed; reads(0) issued
  STAGE_TILE(0, 0);
  STAGE_TILE(1, 1);
  asm volatile("s_waitcnt vmcnt(4)" ::: "memory");
  asm volatile("s_barrier" ::: "memory");
  bf16x8 afA[4], bfA[4], afB[4], bfB[4];
  READS(0, afA, bfA);
  int slc = 0;

#define GEMM_ITER(t_, afC, bfC, afN, bfN)                         \
  {                                                               \
    asm volatile("s_waitcnt lgkmcnt(0)" ::: "memory");            \
    __builtin_amdgcn_sched_barrier(0);                            \
    if ((t_) + 2 < NT) {                                          \
      const int snx_ = (slc + 2 >= 3) ? slc - 1 : slc + 2;        \
      STAGE_TILE((t_) + 2, snx_);                                 \
      asm volatile("s_waitcnt vmcnt(4)" ::: "memory");            \
    } else if ((t_) + 1 < NT) {                                   \
      asm volatile("s_waitcnt vmcnt(0)" ::: "memory");            \
    }                                                             \
    asm volatile("s_barrier" ::: "memory");                       \
    const int srd_ = (slc + 1 >= 3) ? 0 : slc + 1;                \
    if ((t_) + 1 < NT) READS(srd_, afN, bfN);                     \
    __builtin_amdgcn_sched_barrier(0);                            \
    __builtin_amdgcn_s_setprio(1);                                \
    _Pragma("unroll") for (int i_ = 0; i_ < 4; i_++)              \
        _Pragma("unroll") for (int j_ = 0; j_ < 4; j_++)          \
            acc[i_][j_] = MFMA16(afC[i_], bfC[j_], acc[i_][j_]);  \
    __builtin_amdgcn_s_setprio(0);                                \
    slc = srd_;                                                   \
  }

  for (int t = 0; t < NT; t += 2) {
    GEMM_ITER(t, afA, bfA, afB, bfB);
    GEMM_ITER(t + 1, afB, bfB, afA, bfA);
  }
#undef GEMM_ITER
#undef READS
#undef STAGE_TILE

#pragma unroll
  for (int i = 0; i < 4; i++) {
#pragma unroll
    for (int j = 0; j < 4; j++) {
      const int col = tn + wc + j * 16 + l16;
      float bv = 0.f;
      if (HAS_BIAS) bv = bias[col];
#pragma unroll
      for (int r = 0; r < 4; r++) {
        const long row = (long)tm + wr + i * 16 + g * 4 + r;
        float v = acc[i][j][r] + bv;
        if (OUT_BF16)
          ((bf16*)Cp)[row * N + col] = (bf16)v;
        else
          ((float*)Cp)[row * N + col] = v;
      }
    }
  }
}

// ---- 4 small projections FIRST (K=2048, 64 K-steps: the longest blocks in
// the grid -> dispatch them at indices 0..79 so they start at t=0 and their
// duration hides under the Q-proj phase instead of forming a ~4%-occupancy
// tail after the 1280 Q blocks drain), then Q-proj (1280 blocks, XCD
// supertile at q = i-80; 80 % 8 == 0 keeps the (q&7) <-> XCD alignment). ----
__global__ __launch_bounds__(256) void gemm_qproj_small(
    const bf16* __restrict__ xb, const bf16* __restrict__ WqT,
    bf16* __restrict__ qb, const bf16* __restrict__ ctxb,
    const bf16* __restrict__ imgb, const bf16* __restrict__ WkT,
    const bf16* __restrict__ WvT, const bf16* __restrict__ WkipT,
    const bf16* __restrict__ WvipT, bf16* __restrict__ kb,
    bf16* __restrict__ vb, bf16* __restrict__ ipkb, bf16* __restrict__ ipvb) {
  const int i = blockIdx.x;
  const bf16 *A, *Bt;
  bf16* C;
  int K, tm, tn;
  if (i >= 80) {
    const int q = i - 80;       // 0..1279
    const int local = q >> 3;   // 0..159
    A = xb; Bt = WqT; C = qb; K = 1280;
    tm = ((q & 7) * 16 + local / 10) * 128;
    tn = (local % 10) * 128;
  } else {
    // 80 valid small-GEMM tiles, densely packed (no dead blocks):
    // 0..29 -> K-proj (3x10), 30..59 -> V-proj (3x10),
    // 60..69 -> ipK (1x10), 70..79 -> ipV (1x10)
    int z, bx, by;
    if (i < 60) {
      z = i / 30;
      const int r = i % 30;
      bx = r % 3;
      by = r / 3;
    } else {
      z = 2 + (i - 60) / 10;
      bx = 0;
      by = (i - 60) % 10;
    }
    A = (z < 2) ? ctxb : imgb;
    Bt = (z == 0) ? WkT : (z == 1) ? WvT : (z == 2) ? WkipT : WvipT;
    C = (z == 0) ? kb : (z == 1) ? vb : (z == 2) ? ipkb : ipvb;
    K = 2048;
    tm = bx * 128;
    tn = by * 128;
  }
  gemm_bt_core<true, false>(A, Bt, C, nullptr, K, 1280, tm, tn);
}

// ---- out-proj, 1D grid 1280, same supertile map ----
__global__ __launch_bounds__(256) void gemm_f32out_bias(
    const bf16* __restrict__ A, const bf16* __restrict__ Bt,
    float* __restrict__ C, const float* __restrict__ bias, int K, int N) {
  const int i = blockIdx.x;
  const int local = i >> 3;
  const int tm = ((i & 7) * 16 + local / 10) * 128;
  const int tn = (local % 10) * 128;
  gemm_bt_core<false, true>(A, Bt, C, bias, K, N, tm, tn);
}

// ---------------- fused dual cross-attention (unchanged) ----------------
__global__ __launch_bounds__(256) void attention_kernel(
    const bf16* __restrict__ q, const bf16* __restrict__ k,
    const bf16* __restrict__ v, const bf16* __restrict__ ipk,
    const bf16* __restrict__ ipv, bf16* __restrict__ out) {
  __shared__ bf16 Kl[96 * 64];
  __shared__ bf16 Vt[64 * 104];
  __shared__ bf16 Pl[4][16 * 104];

  const int b = blockIdx.z, h = blockIdx.y, qblk = blockIdx.x;
  const int tid = threadIdx.x;

  {
    uint32_t* vz = (uint32_t*)Vt;
    for (int i = tid; i < 64 * 104 / 2; i += 256) vz[i] = 0;
  }
  __syncthreads();

  for (int c = tid; c < 77 * 8; c += 256) {
    const int row = c >> 3, d0 = (c & 7) * 8;
    const long src = (long)(b * 77 + row) * 1280 + h * 64 + d0;
    bf16x8 kk = *(const bf16x8*)&k[src];
    *(bf16x8*)&Kl[row * 64 + (d0 ^ ((row & 7) << 3))] = kk;
    bf16x8 vv = *(const bf16x8*)&v[src];
#pragma unroll
    for (int i2 = 0; i2 < 8; i2++) Vt[(d0 + i2) * 104 + row] = vv[i2];
  }
  if (tid < 16 * 8) {
    const int r = tid >> 3, d0 = (tid & 7) * 8;
    const int row = 80 + r;
    const long src = (long)(b * 16 + r) * 1280 + h * 64 + d0;
    bf16x8 kk = *(const bf16x8*)&ipk[src];
    *(bf16x8*)&Kl[row * 64 + (d0 ^ ((row & 7) << 3))] = kk;
    bf16x8 vv = *(const bf16x8*)&ipv[src];
#pragma unroll
    for (int i2 = 0; i2 < 8; i2++) Vt[(d0 + i2) * 104 + row] = vv[i2];
  }
  __syncthreads();

  const int wave = tid >> 6, lane = tid & 63;
  const int g = lane >> 4, l16 = lane & 15;
  const float sc = 0.125f * 1.44269504f;  // 1/sqrt(64) * log2(e)

  for (int it = 0; it < 2; it++) {
    const long qrow = (long)b * 4096 + qblk * 128 + wave * 32 + it * 16;
    bf16x8 qf[2];
#pragma unroll
    for (int ks = 0; ks < 2; ks++)
      qf[ks] = *(const bf16x8*)&q[(qrow + l16) * 1280 + h * 64 + ks * 32 + g * 8];

    f32x4 lt[6];
#pragma unroll
    for (int t = 0; t < 6; t++) {
      f32x4 a = {0.f, 0.f, 0.f, 0.f};
#pragma unroll
      for (int ks = 0; ks < 2; ks++) {
        const int row = t * 16 + l16;
        const int d = (ks * 32 + g * 8) ^ ((row & 7) << 3);
        bf16x8 kb8 = *(const bf16x8*)&Kl[row * 64 + d];
        a = MFMA16(qf[ks], kb8, a);
      }
      lt[t] = a;
    }

    float p[6][4];
#pragma unroll
    for (int r = 0; r < 4; r++) {
      float lv[5], m = -3e38f;
#pragma unroll
      for (int t = 0; t < 5; t++) {
        const int kv = t * 16 + l16;
        lv[t] = (kv < 77) ? lt[t][r] * sc : -3e38f;
        m = fmaxf(m, lv[t]);
      }
      for (int msk = 1; msk < 16; msk <<= 1) m = fmaxf(m, __shfl_xor(m, msk, 16));
      float s = 0.f;
#pragma unroll
      for (int t = 0; t < 5; t++) {
        const float pp = exp2f(lv[t] - m);
        p[t][r] = pp;
        s += pp;
      }
      for (int msk = 1; msk < 16; msk <<= 1) s += __shfl_xor(s, msk, 16);
      const float inv = 1.f / s;
#pragma unroll
      for (int t = 0; t < 5; t++) p[t][r] *= inv;
      const float l5 = lt[5][r] * sc;
      float m2 = l5;
      for (int msk = 1; msk < 16; msk <<= 1) m2 = fmaxf(m2, __shfl_xor(m2, msk, 16));
      const float p5 = exp2f(l5 - m2);
      float s2 = p5;
      for (int msk = 1; msk < 16; msk <<= 1) s2 += __shfl_xor(s2, msk, 16);
      p[5][r] = p5 / s2;
    }

#pragma unroll
    for (int t = 0; t < 6; t++)
#pragma unroll
      for (int r = 0; r < 4; r++)
        Pl[wave][(g * 4 + r) * 104 + t * 16 + l16] = (bf16)p[t][r];
    __syncthreads();

    bf16x8 paf[3];
#pragma unroll
    for (int ks = 0; ks < 3; ks++)
      paf[ks] = *(const bf16x8*)&Pl[wave][l16 * 104 + ks * 32 + g * 8];
#pragma unroll
    for (int n = 0; n < 4; n++) {
      f32x4 o = {0.f, 0.f, 0.f, 0.f};
#pragma unroll
      for (int ks = 0; ks < 3; ks++) {
        bf16x8 vbf = *(const bf16x8*)&Vt[(n * 16 + l16) * 104 + ks * 32 + g * 8];
        o = MFMA16(paf[ks], vbf, o);
      }
#pragma unroll
      for (int r = 0; r < 4; r++)
        out[(qrow + g * 4 + r) * 1280 + h * 64 + n * 16 + l16] = (bf16)o[r];
    }
    __syncthreads();
  }
}

// ---------------- host launch ----------------
extern "C" void kernel_launch(void* const* d_in, const int* in_sizes, int n_in,
                              void* d_out, int out_size, void* d_ws,
                              size_t ws_size, hipStream_t stream) {
  const float* x = (const float*)d_in[0];
  const float* ctx = (const float*)d_in[1];
  const float* img = (const float*)d_in[2];
  const float* Wq = (const float*)d_in[3];
  const float* Wk = (const float*)d_in[4];
  const float* Wv = (const float*)d_in[5];
  const float* Wkip = (const float*)d_in[6];
  const float* Wvip = (const float*)d_in[7];
  const float* Wo = (const float*)d_in[8];
  const float* bo = (const float*)d_in[9];
  float* out = (float*)d_out;

  bf16* ws = (bf16*)d_ws;
  size_t o = 0;
  auto alloc = [&](size_t n) { bf16* p = ws + o; o += n; return p; };
  bf16* xattn = alloc(16384L * 1280);  // x_bf16, later reused for attn output
  bf16* qb    = alloc(16384L * 1280);
  bf16* WqT   = alloc(1280L * 1280);
  bf16* WoT   = alloc(1280L * 1280);
  bf16* WkT   = alloc(1280L * 2048);
  bf16* WvT   = alloc(1280L * 2048);
  bf16* WkipT = alloc(1280L * 2048);
  bf16* WvipT = alloc(1280L * 2048);
  bf16* ctxb  = alloc(384L * 2048);   // 308 valid rows, padded
  bf16* imgb  = alloc(128L * 2048);   // 64 valid rows, padded
  bf16* kb    = alloc(384L * 1280);
  bf16* vb    = alloc(384L * 1280);
  bf16* ipkb  = alloc(128L * 1280);
  bf16* ipvb  = alloc(128L * 1280);

  // all prep (6 transposes + 3 casts) in one launch
  prep_all<<<dim3(40, 64, 11), dim3(32, 8), 0, stream>>>(
      Wq, Wo, Wk, Wv, Wkip, Wvip, WqT, WoT, WkT, WvT, WkipT, WvipT, x, xattn,
      ctx, ctxb, img, imgb);

  // small projections (long blocks) FIRST, then Q projection supertile
  gemm_qproj_small<<<1360, 256, 0, stream>>>(xattn, WqT, qb, ctxb, imgb, WkT,
                                             WvT, WkipT, WvipT, kb, vb, ipkb,
                                             ipvb);

  // fused dual attention -> xattn (reuses x_bf16 buffer)
  attention_kernel<<<dim3(32, 20, 4), 256, 0, stream>>>(qb, kb, vb, ipkb, ipvb,
                                                        xattn);

  // output projection + bias: out = attn @ Wo + bo (f32 out)
  gemm_f32out_bias<<<1280, 256, 0, stream>>>(xattn, WoT, out, bo, 1280, 1280);
}